// Round 2
// baseline (2557.294 us; speedup 1.0000x reference)
//
#include <hip/hip_runtime.h>

// VQ-VAE VectorQuantizer forward + EMA update, MI355X (gfx950).
// Bit-exactly emulates the numpy fp32 reference's distance computation:
//   dist = pairwise_sum(x*x) - 2*(sgemm FMA chain) + pairwise_sum(w*w)
// because with codes ~U(+-1/8192) the fp32 quantization of dist at ulp(256)
// decides the argmin for ~5% of tokens.

#define NTOK 16384
#define KC   8192
#define DD   256

#define OFF_Q    0
#define OFF_LOSS 4194304
#define OFF_IDX  4194305
#define OFF_W    4210689
#define OFF_CS   6307841
#define OFF_EMA  6316033

#define DECAY_F  0.99f
#define OMD_F    0.01f
#define EPS_F    1e-5f
#define KEPS_F   0.08192f   // K * eps

// ---- numpy-pairwise row squared-norms (n=256): two 128 halves, 8 strided
// accumulators each, combined ((r0+r1)+(r2+r3))+((r4+r5)+(r6+r7)), h0+h1.
// 16 lanes per row; xor-butterfly reproduces the combine tree bit-exactly.
__global__ __launch_bounds__(256) void k_rownorm(const float* __restrict__ a,
                                                 float* __restrict__ outn) {
    const int wave = threadIdx.x >> 6, lane = threadIdx.x & 63;
    const int row  = blockIdx.x * 16 + wave * 4 + (lane >> 4);
    const int p    = lane & 15;
    const int h    = p >> 3, j = p & 7;
    const float* base = a + row * DD + h * 128 + j;
    float v = base[0];
    float r = __fmul_rn(v, v);
    #pragma unroll
    for (int t = 1; t < 16; ++t) {
        v = base[8 * t];
        r = __fadd_rn(r, __fmul_rn(v, v));
    }
    r = __fadd_rn(r, __shfl_xor(r, 1));
    r = __fadd_rn(r, __shfl_xor(r, 2));
    r = __fadd_rn(r, __shfl_xor(r, 4));
    r = __fadd_rn(r, __shfl_xor(r, 8));
    if (p == 0) outn[row] = r;
}

// ---------------- init EMA outputs + zero loss accumulator ----------------
__global__ __launch_bounds__(256) void k_init(const float* __restrict__ emaw,
                                              const float* __restrict__ ecs,
                                              float* __restrict__ out,
                                              float* __restrict__ lossacc) {
    const int i = blockIdx.x * 256 + threadIdx.x;    // grid covers KC*DD = 2M
    out[OFF_EMA + i] = __fmul_rn(DECAY_F, emaw[i]);
    if (i < KC) out[OFF_CS + i] = __fmul_rn(DECAY_F, ecs[i]);
    if (i == 0) *lossacc = 0.0f;
}

// ---------------- argmin distance: tiled fp32 GEMM + running argmin --------
// block: 256 thr (16x16), tile 64 rows x 64 codes, D chunked by 64.
// acc[i][j] is ONE fp32 FMA chain over k=0..255 in ascending order
// (matches BLAS sgemm micro-kernel rounding). dist combined per numpy op
// order: (x2 - 2*xe) + w2, each op rounded once.
__global__ __launch_bounds__(256) void k_argmin(const float* __restrict__ z,
                                                const float* __restrict__ w,
                                                const float* __restrict__ x2v,
                                                const float* __restrict__ w2v,
                                                int* __restrict__ idx_ws,
                                                float* __restrict__ out) {
    __shared__ float Zs[64][64];   // [d-in-chunk][row]  16 KB (transposed)
    __shared__ float Ws[64][64];   // [d-in-chunk][code] 16 KB (transposed)

    const int tid  = threadIdx.x;
    const int tx   = tid & 15;         // code group 0..15 (4 codes each)
    const int ty   = tid >> 4;         // row  group 0..15 (4 rows each)
    const int n0   = blockIdx.x * 64;
    const int lrow = tid & 63;         // staging: row/code within tile
    const int ldg  = tid >> 6;         // staging: 0..3

    float x2r[4];
    #pragma unroll
    for (int i = 0; i < 4; ++i) x2r[i] = x2v[n0 + ty * 4 + i];

    float bestv[4];
    int   bestk[4];
    #pragma unroll
    for (int i = 0; i < 4; ++i) { bestv[i] = 1e30f; bestk[i] = 0; }

    for (int k0 = 0; k0 < KC; k0 += 64) {
        float acc[4][4] = {};
        for (int dt = 0; dt < DD; dt += 64) {
            __syncthreads();   // previous chunk's compute done before overwrite
            #pragma unroll
            for (int p = 0; p < 4; ++p) {
                const int dg = ldg + p * 4;            // 16B group within chunk
                const float4 av = *(const float4*)&z[(n0 + lrow) * DD + dt + dg * 4];
                Zs[dg * 4 + 0][lrow] = av.x; Zs[dg * 4 + 1][lrow] = av.y;
                Zs[dg * 4 + 2][lrow] = av.z; Zs[dg * 4 + 3][lrow] = av.w;
                const float4 bv = *(const float4*)&w[(k0 + lrow) * DD + dt + dg * 4];
                Ws[dg * 4 + 0][lrow] = bv.x; Ws[dg * 4 + 1][lrow] = bv.y;
                Ws[dg * 4 + 2][lrow] = bv.z; Ws[dg * 4 + 3][lrow] = bv.w;
            }
            __syncthreads();
            #pragma unroll 16
            for (int dd = 0; dd < 64; ++dd) {
                const float4 a = *(const float4*)&Zs[dd][ty * 4];  // 4 rows
                const float4 b = *(const float4*)&Ws[dd][tx * 4];  // 4 codes
                acc[0][0] = __fmaf_rn(a.x, b.x, acc[0][0]);
                acc[0][1] = __fmaf_rn(a.x, b.y, acc[0][1]);
                acc[0][2] = __fmaf_rn(a.x, b.z, acc[0][2]);
                acc[0][3] = __fmaf_rn(a.x, b.w, acc[0][3]);
                acc[1][0] = __fmaf_rn(a.y, b.x, acc[1][0]);
                acc[1][1] = __fmaf_rn(a.y, b.y, acc[1][1]);
                acc[1][2] = __fmaf_rn(a.y, b.z, acc[1][2]);
                acc[1][3] = __fmaf_rn(a.y, b.w, acc[1][3]);
                acc[2][0] = __fmaf_rn(a.z, b.x, acc[2][0]);
                acc[2][1] = __fmaf_rn(a.z, b.y, acc[2][1]);
                acc[2][2] = __fmaf_rn(a.z, b.z, acc[2][2]);
                acc[2][3] = __fmaf_rn(a.z, b.w, acc[2][3]);
                acc[3][0] = __fmaf_rn(a.w, b.x, acc[3][0]);
                acc[3][1] = __fmaf_rn(a.w, b.y, acc[3][1]);
                acc[3][2] = __fmaf_rn(a.w, b.z, acc[3][2]);
                acc[3][3] = __fmaf_rn(a.w, b.w, acc[3][3]);
            }
        }
        // dist = (x2 - 2*xe) + w2, per-op fp32 rounding; strict '<' keeps
        // first occurrence (np.argmin tie rule), codes ascend in this loop.
        #pragma unroll
        for (int j = 0; j < 4; ++j) {
            const int   code = k0 + tx * 4 + j;
            const float w2   = w2v[code];
            #pragma unroll
            for (int i = 0; i < 4; ++i) {
                const float dv = __fadd_rn(
                    __fsub_rn(x2r[i], __fmul_rn(2.0f, acc[i][j])), w2);
                if (dv < bestv[i]) { bestv[i] = dv; bestk[i] = code; }
            }
        }
    }

    // reduce the 16 candidates per row (lanes sharing ty are 16 consecutive)
    #pragma unroll
    for (int i = 0; i < 4; ++i) {
        float bv = bestv[i];
        int   bk = bestk[i];
        #pragma unroll
        for (int off = 8; off; off >>= 1) {
            const float ov = __shfl_down(bv, off, 16);
            const int   ok = __shfl_down(bk, off, 16);
            if (ov < bv || (ov == bv && ok < bk)) { bv = ov; bk = ok; }
        }
        if (tx == 0) {
            const int row = ty * 4 + i;
            idx_ws[n0 + row]        = bk;
            out[OFF_IDX + n0 + row] = (float)bk;
        }
    }
}

// ---------------- gather quantized + loss partial + EMA scatter ------------
__global__ __launch_bounds__(256) void k_scatter(const float* __restrict__ z,
                                                 const float* __restrict__ w,
                                                 const int* __restrict__ idx_ws,
                                                 float* __restrict__ out,
                                                 float* __restrict__ lossacc) {
    const int n = blockIdx.x, d = threadIdx.x;
    const int k = idx_ws[n];
    const float zv   = z[n * DD + d];
    const float q    = w[k * DD + d];
    const float diff = __fsub_rn(q, zv);
    out[OFF_Q + n * DD + d] = __fadd_rn(zv, diff);   // straight-through value

    float s = __fmul_rn(diff, diff);
    #pragma unroll
    for (int off = 32; off; off >>= 1) s += __shfl_down(s, off, 64);
    __shared__ float ps[4];
    if ((d & 63) == 0) ps[d >> 6] = s;
    __syncthreads();
    if (d == 0) atomicAdd(lossacc, ps[0] + ps[1] + ps[2] + ps[3]);

    atomicAdd(&out[OFF_EMA + k * DD + d], __fmul_rn(OMD_F, zv));
    if (d == 0) atomicAdd(&out[OFF_CS + k], OMD_F);
}

// ---------------- n = sum(new_cluster_size); finalize loss -----------------
__global__ __launch_bounds__(256) void k_nsum(float* __restrict__ out,
                                              const float* __restrict__ lossacc,
                                              float* __restrict__ nsum) {
    const int t = threadIdx.x;
    float s = 0.0f;
    for (int i = t; i < KC; i += 256) s += out[OFF_CS + i];
    #pragma unroll
    for (int off = 32; off; off >>= 1) s += __shfl_down(s, off, 64);
    __shared__ float ps[4];
    if ((t & 63) == 0) ps[t >> 6] = s;
    __syncthreads();
    if (t == 0) {
        *nsum = ps[0] + ps[1] + ps[2] + ps[3];
        // loss = codebook + 0.25*commitment; both equal mean((q-z)^2)
        out[OFF_LOSS] = 1.25f * (*lossacc) / 4194304.0f;
    }
}

// ---------------- new_weight = new_ema_w / laplace(cluster_size) -----------
__global__ __launch_bounds__(256) void k_neww(float* __restrict__ out,
                                              const float* __restrict__ nsum) {
    const int k = blockIdx.x, d = threadIdx.x;
    const float n  = *nsum;
    const float cs = __fmul_rn(__fdiv_rn(__fadd_rn(out[OFF_CS + k], EPS_F),
                                         __fadd_rn(n, KEPS_F)), n);
    out[OFF_W + k * DD + d] = __fdiv_rn(out[OFF_EMA + k * DD + d], cs);
}

extern "C" void kernel_launch(void* const* d_in, const int* in_sizes, int n_in,
                              void* d_out, int out_size, void* d_ws, size_t ws_size,
                              hipStream_t stream) {
    const float* z    = (const float*)d_in[0];
    const float* w    = (const float*)d_in[1];
    const float* ecs  = (const float*)d_in[2];
    const float* emaw = (const float*)d_in[3];
    float* out = (float*)d_out;

    int*   idx_ws  = (int*)d_ws;                       // NTOK ints
    float* x2v     = (float*)d_ws + NTOK;              // NTOK floats
    float* w2v     = x2v + NTOK;                       // KC floats
    float* lossacc = w2v + KC;                         // 1 float
    float* nsum    = lossacc + 1;                      // 1 float

    k_rownorm<<<NTOK / 16,      256, 0, stream>>>(z, x2v);
    k_rownorm<<<KC / 16,        256, 0, stream>>>(w, w2v);
    k_init  <<<(KC * DD) / 256, 256, 0, stream>>>(emaw, ecs, out, lossacc);
    k_argmin<<<NTOK / 64,       256, 0, stream>>>(z, w, x2v, w2v, idx_ws, out);
    k_scatter<<<NTOK,           256, 0, stream>>>(z, w, idx_ws, out, lossacc);
    k_nsum  <<<1,               256, 0, stream>>>(out, lossacc, nsum);
    k_neww  <<<KC,              256, 0, stream>>>(out, nsum);
}

// Round 3
// 1150.975 us; speedup vs baseline: 2.2219x; 2.2219x over previous
//
#include <hip/hip_runtime.h>

// VQ-VAE VectorQuantizer forward + EMA update, MI355X (gfx950).
// Distance argmin bit-exactly emulates the numpy fp32 reference:
//   dist = pairwise_sum(x*x) - 2*(sgemm single-FMA-chain) + pairwise_sum(w*w)
// R2: K-split x8, 128x128 tiles, 8x8 acc/thread, global_load_lds staging
// from pre-transposed z/w (stashed in d_out regions written later).

#define NTOK 16384
#define KC   8192
#define DD   256

#define OFF_Q    0
#define OFF_LOSS 4194304
#define OFF_IDX  4194305
#define OFF_W    4210689
#define OFF_CS   6307841
#define OFF_EMA  6316033

#define DECAY_F  0.99f
#define OMD_F    0.01f
#define EPS_F    1e-5f
#define KEPS_F   0.08192f   // K * eps

typedef __attribute__((address_space(3))) unsigned int lds_u;
typedef const __attribute__((address_space(1))) unsigned int glob_u;

// ---------------- 32x32 LDS transpose (coalesced both sides) ---------------
__global__ __launch_bounds__(256) void k_tr(const float* __restrict__ in,
                                            float* __restrict__ outT,
                                            int R, int C) {
    __shared__ float s[32][33];
    const int tx = threadIdx.x & 31, ty = threadIdx.x >> 5;
    const int c0 = blockIdx.x * 32, r0 = blockIdx.y * 32;
    #pragma unroll
    for (int i = 0; i < 4; ++i)
        s[ty + i * 8][tx] = in[(size_t)(r0 + ty + i * 8) * C + c0 + tx];
    __syncthreads();
    #pragma unroll
    for (int i = 0; i < 4; ++i)
        outT[(size_t)(c0 + ty + i * 8) * R + r0 + tx] = s[tx][ty + i * 8];
}

// ---- numpy-pairwise row squared-norms (n=256): two 128 halves, 8 strided
// accumulators each, butterfly combine — bit-exact vs numpy pairwise sum.
__global__ __launch_bounds__(256) void k_rownorm(const float* __restrict__ a,
                                                 float* __restrict__ outn) {
    const int wave = threadIdx.x >> 6, lane = threadIdx.x & 63;
    const int row  = blockIdx.x * 16 + wave * 4 + (lane >> 4);
    const int p    = lane & 15;
    const int h    = p >> 3, j = p & 7;
    const float* base = a + row * DD + h * 128 + j;
    float v = base[0];
    float r = __fmul_rn(v, v);
    #pragma unroll
    for (int t = 1; t < 16; ++t) {
        v = base[8 * t];
        r = __fadd_rn(r, __fmul_rn(v, v));
    }
    r = __fadd_rn(r, __shfl_xor(r, 1));
    r = __fadd_rn(r, __shfl_xor(r, 2));
    r = __fadd_rn(r, __shfl_xor(r, 4));
    r = __fadd_rn(r, __shfl_xor(r, 8));
    if (p == 0) outn[row] = r;
}

// ---------------- argmin: K-split fp32 GEMM, 128 rows x 128 codes/tile -----
// grid = 1024: split = blockIdx&7 (→ one XCD per split: its 1MB wT chunk
// stays L2-resident), rb = blockIdx>>3. Each block: 8 code tiles x full D.
// acc[i][j] = single fp32 FMA chain over k ascending (BLAS-exact).
__global__ __launch_bounds__(256, 4) void k_argmin(
        const float* __restrict__ zT, const float* __restrict__ wT,
        const float* __restrict__ x2v, const float* __restrict__ w2v,
        float* __restrict__ vbuf, int* __restrict__ kbuf) {
    __shared__ float Zs[32][128];   // [d][row]  16 KB
    __shared__ float Ws[32][128];   // [d][code] 16 KB

    const int tid   = threadIdx.x;
    const int split = blockIdx.x & 7;
    const int rb    = blockIdx.x >> 3;
    const int n0    = rb * 128;
    const int cbase = split * 1024;
    const int tx4   = (tid & 15) * 4;
    const int ty4   = (tid >> 4) * 4;
    const int l     = tid & 63;
    const int wv    = tid >> 6;
    const int lcol  = (l & 31) * 4;
    const int lrow2 = l >> 5;

    float bestv[8];
    int   bestk[8];
    #pragma unroll
    for (int i = 0; i < 8; ++i) { bestv[i] = 1e30f; bestk[i] = 0; }

    for (int kt = 0; kt < 8; ++kt) {
        const int c0 = cbase + kt * 128;
        float acc[8][8] = {};
        for (int dt = 0; dt < 8; ++dt) {
            const int d0 = dt * 32;
            __syncthreads();   // previous chunk's reads done before overwrite
            #pragma unroll
            for (int q = 0; q < 4; ++q) {
                const int m  = wv * 4 + q;        // 0..15: 2 d-rows each
                const int dd = m * 2 + lrow2;     // 0..31
                const float* gz = zT + (size_t)(d0 + dd) * NTOK + n0 + lcol;
                const float* gw = wT + (size_t)(d0 + dd) * KC   + c0 + lcol;
                __builtin_amdgcn_global_load_lds(
                    (glob_u*)gz, (lds_u*)((char*)&Zs[0][0] + m * 1024 + l * 16),
                    16, 0, 0);
                __builtin_amdgcn_global_load_lds(
                    (glob_u*)gw, (lds_u*)((char*)&Ws[0][0] + m * 1024 + l * 16),
                    16, 0, 0);
            }
            __syncthreads();
            #pragma unroll 8
            for (int dd = 0; dd < 32; ++dd) {
                const float4 a0 = *(const float4*)&Zs[dd][ty4];
                const float4 a1 = *(const float4*)&Zs[dd][64 + ty4];
                const float4 b0 = *(const float4*)&Ws[dd][tx4];
                const float4 b1 = *(const float4*)&Ws[dd][64 + tx4];
                const float av[8] = {a0.x, a0.y, a0.z, a0.w, a1.x, a1.y, a1.z, a1.w};
                const float bw[8] = {b0.x, b0.y, b0.z, b0.w, b1.x, b1.y, b1.z, b1.w};
                #pragma unroll
                for (int i = 0; i < 8; ++i)
                    #pragma unroll
                    for (int j = 0; j < 8; ++j)
                        acc[i][j] = __fmaf_rn(av[i], bw[j], acc[i][j]);
            }
        }
        // dist = (x2 - 2*xe) + w2, per-op fp32 rounding; explicit (==, k<)
        // tie-break == np.argmin first-occurrence.
        #pragma unroll
        for (int j = 0; j < 8; ++j) {
            const int   code = c0 + ((j < 4) ? (tx4 + j) : (64 + tx4 + j - 4));
            const float w2   = w2v[code];
            #pragma unroll
            for (int i = 0; i < 8; ++i) {
                const int   row = n0 + ((i < 4) ? (ty4 + i) : (64 + ty4 + i - 4));
                const float x2  = x2v[row];
                const float dv  = __fadd_rn(
                    __fsub_rn(x2, __fmul_rn(2.0f, acc[i][j])), w2);
                if (dv < bestv[i] || (dv == bestv[i] && code < bestk[i])) {
                    bestv[i] = dv; bestk[i] = code;
                }
            }
        }
    }

    // reduce across tx (16 consecutive lanes share ty)
    #pragma unroll
    for (int i = 0; i < 8; ++i) {
        float bv = bestv[i];
        int   bk = bestk[i];
        #pragma unroll
        for (int off = 8; off; off >>= 1) {
            const float ov = __shfl_down(bv, off, 16);
            const int   ok = __shfl_down(bk, off, 16);
            if (ov < bv || (ov == bv && ok < bk)) { bv = ov; bk = ok; }
        }
        if ((tid & 15) == 0) {
            const int row = n0 + ((i < 4) ? (ty4 + i) : (64 + ty4 + i - 4));
            vbuf[split * NTOK + row] = bv;
            kbuf[split * NTOK + row] = bk;
        }
    }
}

// ---------------- combine the 8 split-candidates per row -------------------
__global__ __launch_bounds__(256) void k_reduce(const float* __restrict__ vbuf,
                                                const int* __restrict__ kbuf,
                                                int* __restrict__ idx_ws,
                                                float* __restrict__ out) {
    const int r = blockIdx.x * 256 + threadIdx.x;
    float bv = vbuf[r];
    int   bk = kbuf[r];
    #pragma unroll
    for (int s = 1; s < 8; ++s) {
        const float v = vbuf[s * NTOK + r];
        const int   k = kbuf[s * NTOK + r];
        if (v < bv || (v == bv && k < bk)) { bv = v; bk = k; }
    }
    idx_ws[r] = bk;
    out[OFF_IDX + r] = (float)bk;
}

// ---------------- init EMA outputs + zero loss accumulator -----------------
// (runs AFTER k_reduce: OFF_EMA region doubles as vbuf/kbuf scratch)
__global__ __launch_bounds__(256) void k_init(const float* __restrict__ emaw,
                                              const float* __restrict__ ecs,
                                              float* __restrict__ out,
                                              float* __restrict__ lossacc) {
    const int i = blockIdx.x * 256 + threadIdx.x;    // grid covers KC*DD = 2M
    out[OFF_EMA + i] = __fmul_rn(DECAY_F, emaw[i]);
    if (i < KC) out[OFF_CS + i] = __fmul_rn(DECAY_F, ecs[i]);
    if (i == 0) *lossacc = 0.0f;
}

// ---------------- gather quantized + loss partial + EMA scatter ------------
__global__ __launch_bounds__(256) void k_scatter(const float* __restrict__ z,
                                                 const float* __restrict__ w,
                                                 const int* __restrict__ idx_ws,
                                                 float* __restrict__ out,
                                                 float* __restrict__ lossacc) {
    const int n = blockIdx.x, d = threadIdx.x;
    const int k = idx_ws[n];
    const float zv   = z[n * DD + d];
    const float q    = w[k * DD + d];
    const float diff = __fsub_rn(q, zv);
    out[OFF_Q + n * DD + d] = __fadd_rn(zv, diff);   // straight-through value

    float s = __fmul_rn(diff, diff);
    #pragma unroll
    for (int off = 32; off; off >>= 1) s += __shfl_down(s, off, 64);
    __shared__ float ps[4];
    if ((d & 63) == 0) ps[d >> 6] = s;
    __syncthreads();
    if (d == 0) atomicAdd(lossacc, ps[0] + ps[1] + ps[2] + ps[3]);

    atomicAdd(&out[OFF_EMA + k * DD + d], __fmul_rn(OMD_F, zv));
    if (d == 0) atomicAdd(&out[OFF_CS + k], OMD_F);
}

// ---------------- n = sum(new_cluster_size); finalize loss -----------------
__global__ __launch_bounds__(256) void k_nsum(float* __restrict__ out,
                                              const float* __restrict__ lossacc,
                                              float* __restrict__ nsum) {
    const int t = threadIdx.x;
    float s = 0.0f;
    for (int i = t; i < KC; i += 256) s += out[OFF_CS + i];
    #pragma unroll
    for (int off = 32; off; off >>= 1) s += __shfl_down(s, off, 64);
    __shared__ float ps[4];
    if ((t & 63) == 0) ps[t >> 6] = s;
    __syncthreads();
    if (t == 0) {
        *nsum = ps[0] + ps[1] + ps[2] + ps[3];
        out[OFF_LOSS] = 1.25f * (*lossacc) / 4194304.0f;
    }
}

// ---------------- new_weight = new_ema_w / laplace(cluster_size) -----------
__global__ __launch_bounds__(256) void k_neww(float* __restrict__ out,
                                              const float* __restrict__ nsum) {
    const int k = blockIdx.x, d = threadIdx.x;
    const float n  = *nsum;
    const float cs = __fmul_rn(__fdiv_rn(__fadd_rn(out[OFF_CS + k], EPS_F),
                                         __fadd_rn(n, KEPS_F)), n);
    out[OFF_W + k * DD + d] = __fdiv_rn(out[OFF_EMA + k * DD + d], cs);
}

extern "C" void kernel_launch(void* const* d_in, const int* in_sizes, int n_in,
                              void* d_out, int out_size, void* d_ws, size_t ws_size,
                              hipStream_t stream) {
    const float* z    = (const float*)d_in[0];
    const float* w    = (const float*)d_in[1];
    const float* ecs  = (const float*)d_in[2];
    const float* emaw = (const float*)d_in[3];
    float* out = (float*)d_out;

    // small scratch in ws (same 164 KB footprint that already passed)
    int*   idx_ws  = (int*)d_ws;                       // NTOK ints
    float* x2v     = (float*)d_ws + NTOK;              // NTOK floats
    float* w2v     = x2v + NTOK;                       // KC floats
    float* lossacc = w2v + KC;                         // 1 float
    float* nsum    = lossacc + 1;                      // 1 float

    // big scratch inside not-yet-final d_out regions:
    float* zT   = out + OFF_Q;     // 16384x256 -> 256x16384 (16 MB)
    float* wT   = out + OFF_W;     //  8192x256 -> 256x8192  ( 8 MB)
    float* vbuf = out + OFF_EMA;                    // 8*NTOK floats
    int*   kbuf = (int*)(out + OFF_EMA) + 8 * NTOK; // 8*NTOK ints

    k_tr     <<<dim3(8, 512),     256, 0, stream>>>(z, zT, NTOK, DD);
    k_tr     <<<dim3(8, 256),     256, 0, stream>>>(w, wT, KC, DD);
    k_rownorm<<<NTOK / 16,        256, 0, stream>>>(z, x2v);
    k_rownorm<<<KC / 16,          256, 0, stream>>>(w, w2v);
    k_argmin <<<1024,             256, 0, stream>>>(zT, wT, x2v, w2v, vbuf, kbuf);
    k_reduce <<<NTOK / 256,       256, 0, stream>>>(vbuf, kbuf, idx_ws, out);
    k_init   <<<(KC * DD) / 256,  256, 0, stream>>>(emaw, ecs, out, lossacc);
    k_scatter<<<NTOK,             256, 0, stream>>>(z, w, idx_ws, out, lossacc);
    k_nsum   <<<1,                256, 0, stream>>>(out, lossacc, nsum);
    k_neww   <<<KC,               256, 0, stream>>>(out, nsum);
}